// Round 1
// baseline (5395.729 us; speedup 1.0000x reference)
//
#include <hip/hip_runtime.h>

typedef _Float16 f16;
typedef _Float16 f16x8 __attribute__((ext_vector_type(8)));
typedef float f32x4 __attribute__((ext_vector_type(4)));

#define TLEN 2048
#define NGP  640      // padded gate dim: 4 gates x 160
#define HROW 168      // padded LDS row length (bank-conflict break)

__device__ __forceinline__ float sigm(float x) {
    return 1.0f / (1.0f + __expf(-x));
}
__device__ __forceinline__ float tanh_fast(float x) {
    // 1 - 2/(e^{2x}+1): handles +/-inf gracefully (no NaN), no clamps needed
    return 1.0f - 2.0f / (__expf(2.0f * x) + 1.0f);
}

// ---------------------------------------------------------------------------
// Prep: build MFMA B-fragment-ordered fp16 copies of w_ih / w_hh (padded
// 600->640 cols as 4 gates x 160, K padded to 160), and combined bias.
// Fragment layout: [nt(40)][kt(5)][lane(64)][e(8)], n = nt*16 + (lane&15),
// k = kt*32 + (lane>>4)*8 + e.  (Same mapping used for A and B packing, so
// any within-group k-permutation cancels.)
// ---------------------------------------------------------------------------
__global__ void prep_weights(const float* __restrict__ w_ih,
                             const float* __restrict__ w_hh,
                             const float* __restrict__ b_ih,
                             const float* __restrict__ b_hh,
                             f16* __restrict__ wihf, f16* __restrict__ whhf,
                             float* __restrict__ biasp)
{
    const int idx = blockIdx.x * blockDim.x + threadIdx.x;
    const int stride = gridDim.x * blockDim.x;
    for (int i = idx; i < 40 * 5 * 64 * 8; i += stride) {
        const int e = i & 7;
        const int lane = (i >> 3) & 63;
        const int kt = (i >> 9) % 5;
        const int nt = i / 2560;
        const int col = lane & 15, grp = lane >> 4;
        const int G = nt / 10, jt = nt % 10;
        const int j = jt * 16 + col;          // index within gate (0..159)
        const int k = kt * 32 + grp * 8 + e;  // K index (0..159)
        f16 vi = (f16)0.f, vh = (f16)0.f;
        if (j < 150) {
            const int row = G * 150 + j;      // row in original 600-row weight
            if (k < 144) vi = (f16)w_ih[row * 144 + k];
            if (k < 150) vh = (f16)w_hh[row * 150 + k];
        }
        wihf[i] = vi;
        whhf[i] = vh;
    }
    for (int i = idx; i < NGP; i += stride) {
        const int G = i / 160, j = i % 160;
        biasp[i] = (j < 150) ? (b_ih[G * 150 + j] + b_hh[G * 150 + j]) : 0.f;
    }
}

// ---------------------------------------------------------------------------
// Conv 3x3 VALID (17->4) + bias + ReLU, one block per (b,t).
// Writes y in [t*16+b][160] fp16 (K padded 144->160 with zeros) so the gates
// GEMM's M-tiles are (one timestep x 16 batches).
// ---------------------------------------------------------------------------
__global__ __launch_bounds__(64) void conv_relu(
    const float* __restrict__ in, const float* __restrict__ cw,
    const float* __restrict__ cb, f16* __restrict__ y)
{
    __shared__ float s_in[1088];
    __shared__ float s_w[612];
    __shared__ float s_b[4];
    const int bt = blockIdx.x, tid = threadIdx.x;
    const float* ip = in + (size_t)bt * 1088;
    #pragma unroll
    for (int i = 0; i < 17; ++i) s_in[tid + i * 64] = ip[tid + i * 64];
    for (int i = tid; i < 612; i += 64) s_w[i] = cw[i];
    if (tid < 4) s_b[tid] = cb[tid];
    __syncthreads();
    const int b = bt >> 11, t = bt & 2047;
    f16* yr = y + (size_t)(t * 16 + b) * 160;
    for (int i = tid; i < 160; i += 64) {
        float v = 0.f;
        if (i < 144) {
            const int oc = i / 36, rr = i % 36, oy = rr / 6, ox = rr % 6;
            float acc = s_b[oc];
            const float* wp = s_w + oc * 153;
            const float* bp = s_in + oy * 8 + ox;
            #pragma unroll
            for (int ic = 0; ic < 17; ++ic)
                #pragma unroll
                for (int ky = 0; ky < 3; ++ky)
                    #pragma unroll
                    for (int kx = 0; kx < 3; ++kx)
                        acc += bp[ic * 64 + ky * 8 + kx] * wp[ic * 9 + ky * 3 + kx];
            v = fmaxf(acc, 0.f);
        }
        yr[i] = (f16)v;
    }
}

// ---------------------------------------------------------------------------
// gates_x = y @ w_ih^T + (b_ih + b_hh).  One block (10 waves) per timestep.
// Wave wv owns j-slice [16*wv,16*wv+16) for all 4 gates.  Output fp16,
// layout [t*16+b][640] so scan loads and these stores are both coalesced.
// ---------------------------------------------------------------------------
__global__ __launch_bounds__(640, 1) void gates_gemm(
    const f16* __restrict__ y, const f16* __restrict__ wihf,
    const float* __restrict__ biasp, f16* __restrict__ gates)
{
    const int tid = threadIdx.x, wv = tid >> 6, lane = tid & 63;
    const int col = lane & 15, grp = lane >> 4;
    const int t = blockIdx.x;
    f16x8 a[5];
    const f16* yr = y + (size_t)(t * 16 + col) * 160;
    #pragma unroll
    for (int kt = 0; kt < 5; ++kt)
        a[kt] = *(const f16x8*)(yr + kt * 32 + grp * 8);
    const int n0 = wv * 16 + col;
    #pragma unroll
    for (int G = 0; G < 4; ++G) {
        f32x4 acc = {0.f, 0.f, 0.f, 0.f};
        const f16* wf = wihf + (size_t)((G * 10 + wv) * 5) * 512;
        #pragma unroll
        for (int kt = 0; kt < 5; ++kt) {
            f16x8 bf = *(const f16x8*)(wf + kt * 512 + lane * 8);
            acc = __builtin_amdgcn_mfma_f32_16x16x32_f16(a[kt], bf, acc, 0, 0, 0);
        }
        const int n = G * 160 + n0;
        const float bb = biasp[n];
        #pragma unroll
        for (int r = 0; r < 4; ++r)
            gates[(size_t)(t * 16 + grp * 4 + r) * NGP + n] = (f16)(acc[r] + bb);
    }
}

// ---------------------------------------------------------------------------
// Persistent single-workgroup LSTM scan.  640 threads = 10 waves; wave wv
// owns j-slice [16wv,16wv+16) x all 4 gates, so i/f/g/o and the c/h update
// are lane-local in the MFMA C layout (col=lane&15 -> j, row=(lane>>4)*4+r
// -> batch).  w_hh B-fragments live in VGPRs for the whole kernel; h is
// double-buffered fp16 in LDS (row padded to 168 to break bank conflicts).
// One barrier per step.
// ---------------------------------------------------------------------------
__global__ __launch_bounds__(640, 1) void lstm_scan(
    const f16* __restrict__ gates, const f16* __restrict__ whhf,
    const float* __restrict__ last_w, const float* __restrict__ last_b,
    float* __restrict__ out)
{
    __shared__ f16 hbuf[2][16][HROW];
    const int tid = threadIdx.x, wv = tid >> 6, lane = tid & 63;
    const int col = lane & 15, grp = lane >> 4;

    for (int i = tid; i < 2 * 16 * HROW; i += 640) ((f16*)hbuf)[i] = (f16)0.f;

    f16x8 bfrag[4][5];
    #pragma unroll
    for (int G = 0; G < 4; ++G)
        #pragma unroll
        for (int kt = 0; kt < 5; ++kt)
            bfrag[G][kt] =
                *(const f16x8*)(whhf + (size_t)(((G * 10 + wv) * 5 + kt) * 64 + lane) * 8);

    float cst[4] = {0.f, 0.f, 0.f, 0.f};
    const int n0 = wv * 16 + col;
    __syncthreads();

    for (int t = 0; t < TLEN; ++t) {
        const int cur = t & 1;
        const f16* xg = gates + (size_t)t * (16 * NGP);

        // Prefetch this step's gates_x early (independent of h).
        float xv[4][4];
        #pragma unroll
        for (int G = 0; G < 4; ++G)
            #pragma unroll
            for (int r = 0; r < 4; ++r)
                xv[G][r] = (float)xg[(grp * 4 + r) * NGP + G * 160 + n0];

        f16x8 a[5];
        #pragma unroll
        for (int kt = 0; kt < 5; ++kt)
            a[kt] = *(const f16x8*)(&hbuf[cur][col][kt * 32 + grp * 8]);

        f32x4 acc[4];
        #pragma unroll
        for (int G = 0; G < 4; ++G) {
            f32x4 v = {0.f, 0.f, 0.f, 0.f};
            #pragma unroll
            for (int kt = 0; kt < 5; ++kt)
                v = __builtin_amdgcn_mfma_f32_16x16x32_f16(a[kt], bfrag[G][kt], v, 0, 0, 0);
            acc[G] = v;
        }

        float hn[4];
        #pragma unroll
        for (int r = 0; r < 4; ++r) {
            const float gi = acc[0][r] + xv[0][r];
            const float gf = acc[1][r] + xv[1][r];
            const float gg = acc[2][r] + xv[2][r];
            const float go = acc[3][r] + xv[3][r];
            const float c = sigm(gf) * cst[r] + sigm(gi) * tanh_fast(gg);
            cst[r] = c;
            hn[r] = sigm(go) * tanh_fast(c);
        }
        #pragma unroll
        for (int r = 0; r < 4; ++r)
            hbuf[cur ^ 1][grp * 4 + r][n0] = (f16)hn[r];
        __syncthreads();
    }

    // Final projection: h_T @ last_w^T + last_b  (h_T is in hbuf[0] since
    // step 2047 wrote buffer (2047+1)&1 == 0).
    if (tid < 32) {
        const int b = tid >> 1, o = tid & 1;
        float s = last_b[o];
        for (int j = 0; j < 150; ++j)
            s += (float)hbuf[0][b][j] * last_w[o * 150 + j];
        out[b * 2 + o] = s;
    }
}

// ---------------------------------------------------------------------------
extern "C" void kernel_launch(void* const* d_in, const int* in_sizes, int n_in,
                              void* d_out, int out_size, void* d_ws, size_t ws_size,
                              hipStream_t stream) {
    const float* inp    = (const float*)d_in[0];
    const float* conv_w = (const float*)d_in[1];
    const float* conv_b = (const float*)d_in[2];
    const float* w_ih   = (const float*)d_in[3];
    const float* w_hh   = (const float*)d_in[4];
    const float* b_ih   = (const float*)d_in[5];
    const float* b_hh   = (const float*)d_in[6];
    const float* last_w = (const float*)d_in[7];
    const float* last_b = (const float*)d_in[8];
    float* out = (float*)d_out;

    char* ws = (char*)d_ws;
    f16*   y     = (f16*)(ws);                               // 32768*160*2  = 10,485,760
    f16*   gates = (f16*)(ws + 10485760);                    // 32768*640*2  = 41,943,040
    f16*   wihf  = (f16*)(ws + 10485760 + 41943040);         // 204,800
    f16*   whhf  = (f16*)(ws + 10485760 + 41943040 + 204800);// 204,800
    float* biasp = (float*)(ws + 10485760 + 41943040 + 409600); // 2,560

    prep_weights<<<120, 256, 0, stream>>>(w_ih, w_hh, b_ih, b_hh, wihf, whhf, biasp);
    conv_relu<<<32768, 64, 0, stream>>>(inp, conv_w, conv_b, y);
    gates_gemm<<<2048, 640, 0, stream>>>(y, wihf, biasp, gates);
    lstm_scan<<<1, 640, 0, stream>>>(gates, whhf, last_w, last_b, out);
}